// Round 7
// baseline (207.584 us; speedup 1.0000x reference)
//
#include <hip/hip_runtime.h>

#define NB 256
#define NM 128
#define ND 64
#define NH 8

typedef float f32x4 __attribute__((ext_vector_type(4)));
typedef short bf16x8 __attribute__((ext_vector_type(8)));   // 8 bf16 = 4 VGPRs
typedef unsigned short ushort_t;

__device__ __forceinline__ ushort_t f2bf(float f) {   // RNE f32->bf16
    unsigned int x = __float_as_uint(f);
    x += 0x7fffu + ((x >> 16) & 1u);
    return (ushort_t)(x >> 16);
}

// XOR-swizzled LDS indices (T2): col ^= 8*(row&7). Applied on BOTH write and read.
__device__ __forceinline__ int sw64(int row, int col)  { return row * 64  + (col ^ ((row & 7) << 3)); }
__device__ __forceinline__ int sw128(int row, int col) { return row * 128 + (col ^ ((row & 7) << 3)); }

__device__ __forceinline__ f32x4 MFMA(bf16x8 a, bf16x8 b, f32x4 c) {
    return __builtin_amdgcn_mfma_f32_16x16x32_bf16(a, b, c, 0, 0, 0);
}

// ---- prep: transpose weights to bf16 fragment-friendly layout in d_ws ----
// ws (ushort): WqT[512][64] @0, WkT @32768, WvT @65536, WpT[64][512] @98304  (256 KB)
// O buffer (two-kernel path): @131072 ushorts, [256*128][512] bf16 (32 MB)
extern "C" __global__ void geat_prep(const float* __restrict__ Wq,
                                     const float* __restrict__ Wk,
                                     const float* __restrict__ Wv,
                                     const float* __restrict__ Wp,
                                     ushort_t* __restrict__ ws)
{
    int idx = blockIdx.x * 256 + threadIdx.x;   // 0..131071
    int seg = idx >> 15;
    int r = idx & 32767;
    float v;
    if      (seg == 0) v = Wq[(r & 63) * 512 + (r >> 6)];    // WqT[o][d] = Wq[d][o]
    else if (seg == 1) v = Wk[(r & 63) * 512 + (r >> 6)];
    else if (seg == 2) v = Wv[(r & 63) * 512 + (r >> 6)];
    else               v = Wp[(r & 511) * 64 + (r >> 9)];    // WpT[c][k] = Wp[k][c]
    ws[idx] = f2bf(v);
}

// ============================================================================
// Kernel 1: per-(molecule, head) attention. Grid 2048 = b*8+h, 256 thr (4 waves).
// Wave u owns rows mu = 32u .. 32u+31 (2 m-frags). One barrier per block.
// LDS 48 KB -> 3 blocks/CU resident.
// ============================================================================
extern "C" __global__ __launch_bounds__(256, 1)
void geat_attn(const float* __restrict__ x, const int* __restrict__ edges,
               const float* __restrict__ bq, const float* __restrict__ bk,
               const float* __restrict__ bv, const float* __restrict__ ebias,
               const ushort_t* __restrict__ wt, ushort_t* __restrict__ ows)
{
    __shared__ __align__(16) ushort_t sm[24576];  // 48 KB
    ushort_t* QB  = sm;          // [128][64] Q, then P-half staging (wave-private rows)
    ushort_t* KB  = sm + 8192;   // [128][64] K (shared)
    ushort_t* VTB = sm + 16384;  // [64][128] V^T (shared)

    const int bid  = blockIdx.x;
    const int b    = bid >> 3;
    const int h    = bid & 7;
    const int tid  = threadIdx.x;
    const int u    = tid >> 6;          // wave 0..3
    const int lane = tid & 63;
    const int c    = lane & 15;
    const int g    = lane >> 4;
    const int mu   = u * 32;            // wave's rows

    const ushort_t* WqT = wt;
    const ushort_t* WkT = wt + 32768;
    const ushort_t* WvT = wt + 65536;

    // ---- x A-frags (2 m-frags x 2 k-chunks); double as x^T B-frags for V^T ----
    bf16x8 xA[2][2];
#pragma unroll
    for (int mf = 0; mf < 2; ++mf) {
        const float* xb = x + (size_t)b * NM * ND + (mu + mf * 16 + c) * ND;
#pragma unroll
        for (int kt = 0; kt < 2; ++kt) {
            const float4 lo = *(const float4*)&xb[kt * 32 + 8 * g];
            const float4 hi = *(const float4*)&xb[kt * 32 + 8 * g + 4];
            bf16x8 f;
            f[0] = f2bf(lo.x); f[1] = f2bf(lo.y); f[2] = f2bf(lo.z); f[3] = f2bf(lo.w);
            f[4] = f2bf(hi.x); f[5] = f2bf(hi.y); f[6] = f2bf(hi.z); f[7] = f2bf(hi.w);
            xA[mf][kt] = f;
        }
    }

    // ---- edge codes for this wave's S fragments: (m = mu+16mf+4g+r, n = 16nt+c) ----
    unsigned epack[2][8];
    {
        const int* eg = edges + (size_t)b * NM * NM;
#pragma unroll
        for (int mf = 0; mf < 2; ++mf)
#pragma unroll
            for (int nt = 0; nt < 8; ++nt) {
                unsigned pk = 0;
#pragma unroll
                for (int r = 0; r < 4; ++r)
                    pk |= ((unsigned)eg[(mu + mf * 16 + 4 * g + r) * NM + nt * 16 + c] & 0xffu) << (8 * r);
                epack[mf][nt] = pk;
            }
    }

    // ================= Phase A: Q, K (own 32 rows), V^T (own 32 cols) =================
#pragma unroll
    for (int mf = 0; mf < 2; ++mf) {
        int mt = mu + mf * 16;
#pragma unroll
        for (int nt4 = 0; nt4 < 4; ++nt4) {
            int n0 = nt4 * 16;
            float bqv = bq[h * 64 + n0 + c];
            float bkv = bk[h * 64 + n0 + c];
            f32x4 qacc = {bqv, bqv, bqv, bqv};
            f32x4 kacc = {bkv, bkv, bkv, bkv};
#pragma unroll
            for (int kt = 0; kt < 2; ++kt) {
                const bf16x8 wq = *(const bf16x8*)&WqT[(h * 64 + n0 + c) * 64 + kt * 32 + 8 * g];
                const bf16x8 wk = *(const bf16x8*)&WkT[(h * 64 + n0 + c) * 64 + kt * 32 + 8 * g];
                qacc = MFMA(xA[mf][kt], wq, qacc);
                kacc = MFMA(xA[mf][kt], wk, kacc);
            }
#pragma unroll
            for (int r = 0; r < 4; ++r) {
                QB[sw64(mt + 4 * g + r, n0 + c)] = f2bf(qacc[r]);
                KB[sw64(mt + 4 * g + r, n0 + c)] = f2bf(kacc[r]);
            }
        }
    }
#pragma unroll
    for (int cf = 0; cf < 2; ++cf) {      // V^T cols mu+16cf .. +15
        int ct = mu + cf * 16;
#pragma unroll
        for (int dt = 0; dt < 4; ++dt) {
            int d0 = dt * 16;
            f32x4 vacc;
#pragma unroll
            for (int r = 0; r < 4; ++r) vacc[r] = bv[h * 64 + d0 + 4 * g + r];
#pragma unroll
            for (int kt = 0; kt < 2; ++kt) {
                const bf16x8 wv = *(const bf16x8*)&WvT[(h * 64 + d0 + c) * 64 + kt * 32 + 8 * g];
                vacc = MFMA(wv, xA[cf][kt], vacc);
            }
#pragma unroll
            for (int r = 0; r < 4; ++r)
                VTB[sw128(d0 + 4 * g + r, ct + c)] = f2bf(vacc[r]);
        }
    }
    __syncthreads();   // the block's ONLY barrier: KB/VTB visible to all waves

    // ================= Phase B: S = QK^T/8 + bias, leaky, mask, softmax =================
    bf16x8 qA[2][2];
#pragma unroll
    for (int mf = 0; mf < 2; ++mf)
#pragma unroll
        for (int kt = 0; kt < 2; ++kt)
            qA[mf][kt] = *(const bf16x8*)&QB[sw64(mu + mf * 16 + c, kt * 32 + 8 * g)];

    float eb0 = ebias[0 * NH + h], eb1 = ebias[1 * NH + h], eb2 = ebias[2 * NH + h];
    float eb3 = ebias[3 * NH + h], eb4 = ebias[4 * NH + h];

    f32x4 s[2][8];
#pragma unroll
    for (int nt = 0; nt < 8; ++nt) {
        int n0 = nt * 16;
        bf16x8 kf[2];
#pragma unroll
        for (int kt = 0; kt < 2; ++kt)
            kf[kt] = *(const bf16x8*)&KB[sw64(n0 + c, kt * 32 + 8 * g)];
#pragma unroll
        for (int mf = 0; mf < 2; ++mf) {
            f32x4 acc = (f32x4)0.0f;
            acc = MFMA(qA[mf][0], kf[0], acc);
            acc = MFMA(qA[mf][1], kf[1], acc);
#pragma unroll
            for (int r = 0; r < 4; ++r) {
                int e = (epack[mf][nt] >> (8 * r)) & 0xff;
                float bias = (e == 1) ? eb1 : (e == 2) ? eb2 : (e == 3) ? eb3 : (e == 4) ? eb4 : eb0;
                float sv = acc[r] * 0.125f + bias;
                sv = (sv > 0.f) ? sv : 0.2f * sv;      // leaky BEFORE mask (ref order)
                acc[r] = (e > 0) ? sv : -1e9f;
            }
            s[mf][nt] = acc;
        }
    }
    // softmax per row (row = mu+16mf+4g+r): lane-local over nt, then 16-lane butterfly
    f32x4 inv[2];
#pragma unroll
    for (int mf = 0; mf < 2; ++mf) {
        f32x4 mx;
#pragma unroll
        for (int r = 0; r < 4; ++r) {
            float m0 = s[mf][0][r];
#pragma unroll
            for (int nt = 1; nt < 8; ++nt) m0 = fmaxf(m0, s[mf][nt][r]);
            mx[r] = m0;
        }
#pragma unroll
        for (int d = 1; d < 16; d <<= 1)
#pragma unroll
            for (int r = 0; r < 4; ++r) mx[r] = fmaxf(mx[r], __shfl_xor(mx[r], d));
        f32x4 sum = (f32x4)0.0f;
#pragma unroll
        for (int nt = 0; nt < 8; ++nt)
#pragma unroll
            for (int r = 0; r < 4; ++r) {
                float ev = __expf(s[mf][nt][r] - mx[r]);
                s[mf][nt][r] = ev;
                sum[r] += ev;
            }
#pragma unroll
        for (int d = 1; d < 16; d <<= 1)
#pragma unroll
            for (int r = 0; r < 4; ++r) sum[r] += __shfl_xor(sum[r], d);
#pragma unroll
        for (int r = 0; r < 4; ++r) inv[mf][r] = 1.f / sum[r];
    }

    // ================= Phase C: O = P·V in two half-passes (P staged in QB) =================
    f32x4 oacc[2][4];
#pragma unroll
    for (int mf = 0; mf < 2; ++mf)
#pragma unroll
        for (int dt = 0; dt < 4; ++dt) oacc[mf][dt] = (f32x4)0.0f;

#pragma unroll
    for (int half = 0; half < 2; ++half) {
#pragma unroll
        for (int mf = 0; mf < 2; ++mf)
#pragma unroll
            for (int nt = 0; nt < 4; ++nt)
#pragma unroll
                for (int r = 0; r < 4; ++r)
                    QB[sw64(mu + mf * 16 + 4 * g + r, nt * 16 + c)] =
                        f2bf(s[mf][half * 4 + nt][r] * inv[mf][r]);
        bf16x8 pA[2][2];
#pragma unroll
        for (int mf = 0; mf < 2; ++mf)
#pragma unroll
            for (int kt = 0; kt < 2; ++kt)
                pA[mf][kt] = *(const bf16x8*)&QB[sw64(mu + mf * 16 + c, kt * 32 + 8 * g)];
#pragma unroll
        for (int dt = 0; dt < 4; ++dt) {
            int d0 = dt * 16;
            bf16x8 vf[2];
#pragma unroll
            for (int kt = 0; kt < 2; ++kt)
                vf[kt] = *(const bf16x8*)&VTB[sw128(d0 + c, (half * 2 + kt) * 32 + 8 * g)];
#pragma unroll
            for (int mf = 0; mf < 2; ++mf) {
                oacc[mf][dt] = MFMA(pA[mf][0], vf[0], oacc[mf][dt]);
                oacc[mf][dt] = MFMA(pA[mf][1], vf[1], oacc[mf][dt]);
            }
        }
    }

    // ---- O D-frags -> ws O[b*128+m][512] at cols h*64 + d ----
#pragma unroll
    for (int mf = 0; mf < 2; ++mf)
#pragma unroll
        for (int dt = 0; dt < 4; ++dt)
#pragma unroll
            for (int r = 0; r < 4; ++r)
                ows[(((size_t)b * NM + mu + mf * 16 + 4 * g + r) << 9) + h * 64 + dt * 16 + c] =
                    f2bf(oacc[mf][dt][r]);
}

// ============================================================================
// Kernel 2: out = O[32768,512] @ Wp[512,64] + bp. Grid 512 (b, row-half), 256 thr.
// No LDS, no barriers; A/B frags straight from global (L2/L3-resident).
// ============================================================================
extern "C" __global__ __launch_bounds__(256, 1)
void geat_oproj(const ushort_t* __restrict__ ows, const ushort_t* __restrict__ wt,
                const float* __restrict__ bp, float* __restrict__ out)
{
    const ushort_t* WpT = wt + 98304;
    const int bid  = blockIdx.x;
    const int b    = bid >> 1;
    const int rh   = bid & 1;
    const int tid  = threadIdx.x;
    const int u    = tid >> 6;
    const int lane = tid & 63;
    const int c    = lane & 15;
    const int g    = lane >> 4;
    const int mt   = rh * 64 + u * 16;   // wave's 16 rows

    f32x4 acc[4];
#pragma unroll
    for (int nt4 = 0; nt4 < 4; ++nt4) {
        float bpv = bp[nt4 * 16 + c];
        acc[nt4] = (f32x4){bpv, bpv, bpv, bpv};
    }
    const ushort_t* orow = ows + (((size_t)b * NM + mt + c) << 9);
#pragma unroll
    for (int kt = 0; kt < 16; ++kt) {
        const bf16x8 oA = *(const bf16x8*)&orow[kt * 32 + 8 * g];
#pragma unroll
        for (int nt4 = 0; nt4 < 4; ++nt4) {
            const bf16x8 wp = *(const bf16x8*)&WpT[(nt4 * 16 + c) * 512 + kt * 32 + 8 * g];
            acc[nt4] = MFMA(oA, wp, acc[nt4]);
        }
    }
    float* og = out + (size_t)b * NM * ND;
#pragma unroll
    for (int nt4 = 0; nt4 < 4; ++nt4)
#pragma unroll
        for (int r = 0; r < 4; ++r)
            og[(mt + 4 * g + r) * ND + nt4 * 16 + c] = acc[nt4][r];
}

// ============================================================================
// Fallback (round-6 fused, proven): used only if ws_size < weights + O buffer.
// ============================================================================
extern "C" __global__ __launch_bounds__(512, 1)
void geat_mfma(const float* __restrict__ x, const int* __restrict__ edges,
               const float* __restrict__ bq, const float* __restrict__ bk,
               const float* __restrict__ bv, const float* __restrict__ ebias,
               const float* __restrict__ bp, const ushort_t* __restrict__ wt,
               float* __restrict__ out)
{
    __shared__ __align__(16) ushort_t sm[32768];
    ushort_t* QB  = sm;
    ushort_t* KB  = sm + 8192;
    ushort_t* VTB = sm + 16384;
    ushort_t* PB  = sm + 24576;

    const int b    = blockIdx.x;
    const int tid  = threadIdx.x;
    const int w    = tid >> 6;
    const int lane = tid & 63;
    const int c    = lane & 15;
    const int g    = lane >> 4;
    const int mt   = w * 16;

    const ushort_t* WqT = wt;
    const ushort_t* WkT = wt + 32768;
    const ushort_t* WvT = wt + 65536;
    const ushort_t* WpT = wt + 98304;

    bf16x8 xA[2];
    {
        const float* xb = x + (size_t)b * NM * ND + (mt + c) * ND;
#pragma unroll
        for (int kt = 0; kt < 2; ++kt) {
            const float4 lo = *(const float4*)&xb[kt * 32 + 8 * g];
            const float4 hi = *(const float4*)&xb[kt * 32 + 8 * g + 4];
            bf16x8 f;
            f[0] = f2bf(lo.x); f[1] = f2bf(lo.y); f[2] = f2bf(lo.z); f[3] = f2bf(lo.w);
            f[4] = f2bf(hi.x); f[5] = f2bf(hi.y); f[6] = f2bf(hi.z); f[7] = f2bf(hi.w);
            xA[kt] = f;
        }
    }
    unsigned epack[8];
    {
        const int* eg = edges + (size_t)b * NM * NM;
#pragma unroll
        for (int nt = 0; nt < 8; ++nt) {
            unsigned pk = 0;
#pragma unroll
            for (int r = 0; r < 4; ++r)
                pk |= ((unsigned)eg[(mt + 4 * g + r) * NM + nt * 16 + c] & 0xffu) << (8 * r);
            epack[nt] = pk;
        }
    }
    f32x4 projacc[4];
#pragma unroll
    for (int i = 0; i < 4; ++i) projacc[i] = (f32x4)0.0f;

#pragma unroll 1
    for (int h = 0; h < NH; ++h) {
#pragma unroll
        for (int nt4 = 0; nt4 < 4; ++nt4) {
            int n0 = nt4 * 16;
            float bqv = bq[h * 64 + n0 + c];
            float bkv = bk[h * 64 + n0 + c];
            f32x4 qacc = {bqv, bqv, bqv, bqv};
            f32x4 kacc = {bkv, bkv, bkv, bkv};
#pragma unroll
            for (int kt = 0; kt < 2; ++kt) {
                const bf16x8 wq = *(const bf16x8*)&WqT[(h * 64 + n0 + c) * 64 + kt * 32 + 8 * g];
                const bf16x8 wk = *(const bf16x8*)&WkT[(h * 64 + n0 + c) * 64 + kt * 32 + 8 * g];
                qacc = MFMA(xA[kt], wq, qacc);
                kacc = MFMA(xA[kt], wk, kacc);
            }
#pragma unroll
            for (int r = 0; r < 4; ++r) {
                QB[sw64(mt + 4 * g + r, n0 + c)] = f2bf(qacc[r]);
                KB[sw64(mt + 4 * g + r, n0 + c)] = f2bf(kacc[r]);
            }
        }
#pragma unroll
        for (int dt = 0; dt < 4; ++dt) {
            int d0 = dt * 16;
            f32x4 vacc;
#pragma unroll
            for (int r = 0; r < 4; ++r) vacc[r] = bv[h * 64 + d0 + 4 * g + r];
#pragma unroll
            for (int kt = 0; kt < 2; ++kt) {
                const bf16x8 wv = *(const bf16x8*)&WvT[(h * 64 + d0 + c) * 64 + kt * 32 + 8 * g];
                vacc = MFMA(wv, xA[kt], vacc);
            }
#pragma unroll
            for (int r = 0; r < 4; ++r)
                VTB[sw128(d0 + 4 * g + r, mt + c)] = f2bf(vacc[r]);
        }
        __syncthreads();

        bf16x8 qA[2];
#pragma unroll
        for (int kt = 0; kt < 2; ++kt)
            qA[kt] = *(const bf16x8*)&QB[sw64(mt + c, kt * 32 + 8 * g)];

        float eb0 = ebias[0 * NH + h], eb1 = ebias[1 * NH + h], eb2 = ebias[2 * NH + h];
        float eb3 = ebias[3 * NH + h], eb4 = ebias[4 * NH + h];

        f32x4 s[8];
#pragma unroll
        for (int nt = 0; nt < 8; ++nt) {
            int n0 = nt * 16;
            f32x4 acc = (f32x4)0.0f;
#pragma unroll
            for (int kt = 0; kt < 2; ++kt) {
                const bf16x8 kf = *(const bf16x8*)&KB[sw64(n0 + c, kt * 32 + 8 * g)];
                acc = MFMA(qA[kt], kf, acc);
            }
#pragma unroll
            for (int r = 0; r < 4; ++r) {
                int e = (epack[nt] >> (8 * r)) & 0xff;
                float bias = (e == 1) ? eb1 : (e == 2) ? eb2 : (e == 3) ? eb3 : (e == 4) ? eb4 : eb0;
                float sv = acc[r] * 0.125f + bias;
                sv = (sv > 0.f) ? sv : 0.2f * sv;
                acc[r] = (e > 0) ? sv : -1e9f;
            }
            s[nt] = acc;
        }
        f32x4 mx;
#pragma unroll
        for (int r = 0; r < 4; ++r) {
            float m0 = s[0][r];
#pragma unroll
            for (int nt = 1; nt < 8; ++nt) m0 = fmaxf(m0, s[nt][r]);
            mx[r] = m0;
        }
#pragma unroll
        for (int d = 1; d < 16; d <<= 1)
#pragma unroll
            for (int r = 0; r < 4; ++r) mx[r] = fmaxf(mx[r], __shfl_xor(mx[r], d));
        f32x4 sum = (f32x4)0.0f;
#pragma unroll
        for (int nt = 0; nt < 8; ++nt)
#pragma unroll
            for (int r = 0; r < 4; ++r) {
                float ev = __expf(s[nt][r] - mx[r]);
                s[nt][r] = ev;
                sum[r] += ev;
            }
#pragma unroll
        for (int d = 1; d < 16; d <<= 1)
#pragma unroll
            for (int r = 0; r < 4; ++r) sum[r] += __shfl_xor(sum[r], d);
        f32x4 inv;
#pragma unroll
        for (int r = 0; r < 4; ++r) inv[r] = 1.f / sum[r];

        f32x4 oacc[4];
#pragma unroll
        for (int dt = 0; dt < 4; ++dt) oacc[dt] = (f32x4)0.0f;
#pragma unroll
        for (int half = 0; half < 2; ++half) {
#pragma unroll
            for (int nt = 0; nt < 4; ++nt)
#pragma unroll
                for (int r = 0; r < 4; ++r)
                    PB[sw64(mt + 4 * g + r, nt * 16 + c)] = f2bf(s[half * 4 + nt][r] * inv[r]);
            bf16x8 pA[2];
#pragma unroll
            for (int kt = 0; kt < 2; ++kt)
                pA[kt] = *(const bf16x8*)&PB[sw64(mt + c, kt * 32 + 8 * g)];
#pragma unroll
            for (int dt = 0; dt < 4; ++dt) {
                int d0 = dt * 16;
#pragma unroll
                for (int kt = 0; kt < 2; ++kt) {
                    const bf16x8 vf = *(const bf16x8*)&VTB[sw128(d0 + c, (half * 2 + kt) * 32 + 8 * g)];
                    oacc[dt] = MFMA(pA[kt], vf, oacc[dt]);
                }
            }
        }
#pragma unroll
        for (int dt = 0; dt < 4; ++dt)
#pragma unroll
            for (int r = 0; r < 4; ++r)
                QB[sw64(mt + 4 * g + r, dt * 16 + c)] = f2bf(oacc[dt][r]);

        bf16x8 oA[2];
#pragma unroll
        for (int kt = 0; kt < 2; ++kt)
            oA[kt] = *(const bf16x8*)&QB[sw64(mt + c, kt * 32 + 8 * g)];
#pragma unroll
        for (int nt4 = 0; nt4 < 4; ++nt4) {
            int n0 = nt4 * 16;
#pragma unroll
            for (int kt = 0; kt < 2; ++kt) {
                const bf16x8 wp = *(const bf16x8*)&WpT[(n0 + c) * 512 + h * 64 + kt * 32 + 8 * g];
                projacc[nt4] = MFMA(oA[kt], wp, projacc[nt4]);
            }
        }
        __syncthreads();
    }
    {
        float* og = out + (size_t)b * NM * ND;
#pragma unroll
        for (int nt4 = 0; nt4 < 4; ++nt4) {
            int n0 = nt4 * 16;
            float bpv = bp[n0 + c];
#pragma unroll
            for (int r = 0; r < 4; ++r)
                og[(mt + 4 * g + r) * ND + n0 + c] = projacc[nt4][r] + bpv;
        }
    }
}

extern "C" void kernel_launch(void* const* d_in, const int* in_sizes, int n_in,
                              void* d_out, int out_size, void* d_ws, size_t ws_size,
                              hipStream_t stream) {
    const float* x     = (const float*)d_in[0];
    const int*   edges = (const int*)d_in[1];
    const float* Wq    = (const float*)d_in[2];
    const float* bq    = (const float*)d_in[3];
    const float* Wk    = (const float*)d_in[4];
    const float* bk    = (const float*)d_in[5];
    const float* Wv    = (const float*)d_in[6];
    const float* bv    = (const float*)d_in[7];
    const float* eb    = (const float*)d_in[8];
    const float* Wp    = (const float*)d_in[9];
    const float* bp    = (const float*)d_in[10];
    float* out = (float*)d_out;
    ushort_t* ws = (ushort_t*)d_ws;

    hipLaunchKernelGGL(geat_prep, dim3(512), dim3(256), 0, stream, Wq, Wk, Wv, Wp, ws);

    const size_t need = 262144u + (size_t)NB * NM * 512 * sizeof(ushort_t);  // 33.8 MB
    if (ws_size >= need) {
        ushort_t* oexp = ws + 131072;   // O buffer after the weight block
        hipLaunchKernelGGL(geat_attn, dim3(NB * NH), dim3(256), 0, stream,
                           x, edges, bq, bk, bv, eb, ws, oexp);
        hipLaunchKernelGGL(geat_oproj, dim3(NB * 2), dim3(256), 0, stream,
                           oexp, ws, bp, out);
    } else {
        hipLaunchKernelGGL(geat_mfma, dim3(NB), dim3(512), 0, stream,
                           x, edges, bq, bk, bv, eb, bp, ws, out);
    }
}

// Round 8
// 196.676 us; speedup vs baseline: 1.0555x; 1.0555x over previous
//
#include <hip/hip_runtime.h>

#define NB 256
#define NM 128
#define ND 64
#define NH 8

typedef float f32x4 __attribute__((ext_vector_type(4)));
typedef short bf16x8 __attribute__((ext_vector_type(8)));   // 8 bf16 = 4 VGPRs
typedef unsigned short ushort_t;

__device__ __forceinline__ ushort_t f2bf(float f) {   // RNE f32->bf16
    unsigned int x = __float_as_uint(f);
    x += 0x7fffu + ((x >> 16) & 1u);
    return (ushort_t)(x >> 16);
}

// XOR-swizzled LDS indices (T2): col ^= 8*(row&7). Applied on BOTH write and read.
__device__ __forceinline__ int sw64(int row, int col)  { return row * 64  + (col ^ ((row & 7) << 3)); }
__device__ __forceinline__ int sw128(int row, int col) { return row * 128 + (col ^ ((row & 7) << 3)); }

__device__ __forceinline__ f32x4 MFMA(bf16x8 a, bf16x8 b, f32x4 c) {
    return __builtin_amdgcn_mfma_f32_16x16x32_bf16(a, b, c, 0, 0, 0);
}

// ---- prep: transpose weights to bf16 fragment-friendly layout in d_ws ----
// ws (ushort): WqT[512][64] @0, WkT @32768, WvT @65536, WpT[64][512] @98304  (256 KB)
extern "C" __global__ void geat_prep(const float* __restrict__ Wq,
                                     const float* __restrict__ Wk,
                                     const float* __restrict__ Wv,
                                     const float* __restrict__ Wp,
                                     ushort_t* __restrict__ ws)
{
    int idx = blockIdx.x * 256 + threadIdx.x;   // 0..131071
    int seg = idx >> 15;
    int r = idx & 32767;
    float v;
    if      (seg == 0) v = Wq[(r & 63) * 512 + (r >> 6)];    // WqT[o][d] = Wq[d][o]
    else if (seg == 1) v = Wk[(r & 63) * 512 + (r >> 6)];
    else if (seg == 2) v = Wv[(r & 63) * 512 + (r >> 6)];
    else               v = Wp[(r & 511) * 64 + (r >> 9)];    // WpT[c][k] = Wp[k][c]
    ws[idx] = f2bf(v);
}

// ============================================================================
// Fused, head-pipelined kernel. Grid 256 (one molecule/block), 512 thr (8 waves,
// wave w owns rows 16w..16w+15). Double-buffered K/V^T tiles; next head's weight
// fragments are LOADED at iteration start and CONSUMED after attention (T14
// issue-early/consume-late), so L2/L3 weight latency hides under S/softmax/PV.
// One barrier per head (8 + 1 prologue vs 16 in the round-6 structure).
// At grid 256 there is exactly 1 block/CU -> 8 waves -> 2/SIMD; VGPRs up to 256
// are free (256-granule), so ~96 VGPRs of prefetched fragments cost nothing.
// ============================================================================
extern "C" __global__ __launch_bounds__(512, 1)
void geat_pipe(const float* __restrict__ x, const int* __restrict__ edges,
               const float* __restrict__ bq, const float* __restrict__ bk,
               const float* __restrict__ bv, const float* __restrict__ ebias,
               const float* __restrict__ bp, const ushort_t* __restrict__ wt,
               float* __restrict__ out)
{
    __shared__ __align__(16) ushort_t sm[49152];  // 96 KB: 2 x {QB 8192, KB 8192, VTB 8192}

    const int b    = blockIdx.x;
    const int tid  = threadIdx.x;
    const int lane = tid & 63;
    const int c    = lane & 15;
    const int g    = lane >> 4;
    const int mt   = (tid >> 6) * 16;   // wave's 16 output rows

    const ushort_t* WqT = wt;
    const ushort_t* WkT = wt + 32768;
    const ushort_t* WvT = wt + 65536;
    const ushort_t* WpT = wt + 98304;

    // ---- x A-frags (head-invariant); double as x^T B-frags for V^T ----
    bf16x8 xA[2];
    {
        const float* xb = x + (size_t)b * NM * ND + (mt + c) * ND;
#pragma unroll
        for (int kt = 0; kt < 2; ++kt) {
            const float4 lo = *(const float4*)&xb[kt * 32 + 8 * g];
            const float4 hi = *(const float4*)&xb[kt * 32 + 8 * g + 4];
            bf16x8 f;
            f[0] = f2bf(lo.x); f[1] = f2bf(lo.y); f[2] = f2bf(lo.z); f[3] = f2bf(lo.w);
            f[4] = f2bf(hi.x); f[5] = f2bf(hi.y); f[6] = f2bf(hi.z); f[7] = f2bf(hi.w);
            xA[kt] = f;
        }
    }

    // ---- edge codes, head-invariant: (m = mt+4g+r, n = 16nt+c), packed 4x8b ----
    unsigned epack[8];
    {
        const int* eg = edges + (size_t)b * NM * NM;
#pragma unroll
        for (int nt = 0; nt < 8; ++nt) {
            unsigned pk = 0;
#pragma unroll
            for (int r = 0; r < 4; ++r)
                pk |= ((unsigned)eg[(mt + 4 * g + r) * NM + nt * 16 + c] & 0xffu) << (8 * r);
            epack[nt] = pk;
        }
    }

    f32x4 projacc[4];
#pragma unroll
    for (int i = 0; i < 4; ++i) projacc[i] = (f32x4)0.0f;

    // ---- prefetched weight fragments for the NEXT head (96 VGPRs) ----
    bf16x8 wqf[4][2], wkf[4][2], wvf[4][2];

    // issue the 24 global loads for head h2's weight fragments
    auto LOADW = [&](int h2) {
#pragma unroll
        for (int t4 = 0; t4 < 4; ++t4)
#pragma unroll
            for (int kt = 0; kt < 2; ++kt) {
                const int off = (h2 * 64 + t4 * 16 + c) * 64 + kt * 32 + 8 * g;
                wqf[t4][kt] = *(const bf16x8*)&WqT[off];
                wkf[t4][kt] = *(const bf16x8*)&WkT[off];
                wvf[t4][kt] = *(const bf16x8*)&WvT[off];
            }
    };

    // consume the fragments: Q,K (own 16 rows) and V^T (own 16 cols) into buf
    auto PROJC = [&](int h2, ushort_t* buf) {
        ushort_t* QBn  = buf;
        ushort_t* KBn  = buf + 8192;
        ushort_t* VTn  = buf + 16384;
#pragma unroll
        for (int nt4 = 0; nt4 < 4; ++nt4) {
            const int n0 = nt4 * 16;
            f32x4 qacc = (f32x4)0.0f, kacc = (f32x4)0.0f;
#pragma unroll
            for (int kt = 0; kt < 2; ++kt) {
                qacc = MFMA(xA[kt], wqf[nt4][kt], qacc);
                kacc = MFMA(xA[kt], wkf[nt4][kt], kacc);
            }
            const float bqv = bq[h2 * 64 + n0 + c];    // bias after MFMA: off the init path
            const float bkv = bk[h2 * 64 + n0 + c];
#pragma unroll
            for (int r = 0; r < 4; ++r) {
                QBn[sw64(mt + 4 * g + r, n0 + c)] = f2bf(qacc[r] + bqv);
                KBn[sw64(mt + 4 * g + r, n0 + c)] = f2bf(kacc[r] + bkv);
            }
        }
#pragma unroll
        for (int dt = 0; dt < 4; ++dt) {
            const int d0 = dt * 16;
            f32x4 vacc = (f32x4)0.0f;
#pragma unroll
            for (int kt = 0; kt < 2; ++kt)
                vacc = MFMA(wvf[dt][kt], xA[kt], vacc);   // A = WvT rows (d), B = x^T cols
            const float4 bvv = *(const float4*)&bv[h2 * 64 + d0 + 4 * g];
#pragma unroll
            for (int r = 0; r < 4; ++r)
                VTn[sw128(d0 + 4 * g + r, mt + c)] = f2bf(vacc[r] + (&bvv.x)[r]);
        }
    };

    // ---- prologue: head 0 projections into buffer 0 ----
    LOADW(0);
    PROJC(0, sm);
    __syncthreads();

#pragma unroll 1
    for (int h = 0; h < NH; ++h) {
        ushort_t* bufc = sm + (h & 1) * 24576;
        ushort_t* bufn = sm + ((h & 1) ^ 1) * 24576;
        ushort_t* QBc  = bufc;
        ushort_t* KBc  = bufc + 8192;
        ushort_t* VTc  = bufc + 16384;

        // own-row Q fragments (wave-private; written by this wave last iter)
        bf16x8 qA[2];
#pragma unroll
        for (int kt = 0; kt < 2; ++kt)
            qA[kt] = *(const bf16x8*)&QBc[sw64(mt + c, kt * 32 + 8 * g)];

        // T14: issue next head's weight loads NOW, consume after attention
        if (h < NH - 1) LOADW(h + 1);

        const float eb0 = ebias[0 * NH + h], eb1 = ebias[1 * NH + h], eb2 = ebias[2 * NH + h];
        const float eb3 = ebias[3 * NH + h], eb4 = ebias[4 * NH + h];

        // ---- S = QK^T/8 + bias, leaky, mask ----
        f32x4 s[8];
#pragma unroll
        for (int nt = 0; nt < 8; ++nt) {
            const int n0 = nt * 16;
            f32x4 acc = (f32x4)0.0f;
#pragma unroll
            for (int kt = 0; kt < 2; ++kt) {
                const bf16x8 kf = *(const bf16x8*)&KBc[sw64(n0 + c, kt * 32 + 8 * g)];
                acc = MFMA(qA[kt], kf, acc);
            }
#pragma unroll
            for (int r = 0; r < 4; ++r) {
                const int e = (epack[nt] >> (8 * r)) & 0xff;
                const float bias = (e == 1) ? eb1 : (e == 2) ? eb2 : (e == 3) ? eb3 : (e == 4) ? eb4 : eb0;
                float sv = acc[r] * 0.125f + bias;
                sv = (sv > 0.f) ? sv : 0.2f * sv;      // leaky BEFORE mask (ref order)
                acc[r] = (e > 0) ? sv : -1e9f;
            }
            s[nt] = acc;
        }

        // ---- softmax per row: lane-local over nt, then 16-lane butterfly ----
        f32x4 mx;
#pragma unroll
        for (int r = 0; r < 4; ++r) {
            float m0 = s[0][r];
#pragma unroll
            for (int nt = 1; nt < 8; ++nt) m0 = fmaxf(m0, s[nt][r]);
            mx[r] = m0;
        }
#pragma unroll
        for (int d = 1; d < 16; d <<= 1)
#pragma unroll
            for (int r = 0; r < 4; ++r) mx[r] = fmaxf(mx[r], __shfl_xor(mx[r], d));
        f32x4 sum = (f32x4)0.0f;
#pragma unroll
        for (int nt = 0; nt < 8; ++nt)
#pragma unroll
            for (int r = 0; r < 4; ++r) {
                const float ev = __expf(s[nt][r] - mx[r]);
                s[nt][r] = ev;
                sum[r] += ev;
            }
#pragma unroll
        for (int d = 1; d < 16; d <<= 1)
#pragma unroll
            for (int r = 0; r < 4; ++r) sum[r] += __shfl_xor(sum[r], d);
        f32x4 inv;
#pragma unroll
        for (int r = 0; r < 4; ++r) inv[r] = 1.f / sum[r];

        // ---- O = P·V in two half-passes, P staged in QBc (Q is dead; rows wave-private) ----
        f32x4 oacc[4];
#pragma unroll
        for (int dt = 0; dt < 4; ++dt) oacc[dt] = (f32x4)0.0f;
#pragma unroll
        for (int half = 0; half < 2; ++half) {
#pragma unroll
            for (int nt = 0; nt < 4; ++nt)
#pragma unroll
                for (int r = 0; r < 4; ++r)
                    QBc[sw64(mt + 4 * g + r, nt * 16 + c)] = f2bf(s[half * 4 + nt][r] * inv[r]);
            bf16x8 pA[2];
#pragma unroll
            for (int kt = 0; kt < 2; ++kt)
                pA[kt] = *(const bf16x8*)&QBc[sw64(mt + c, kt * 32 + 8 * g)];
#pragma unroll
            for (int dt = 0; dt < 4; ++dt) {
                const int d0 = dt * 16;
#pragma unroll
                for (int kt = 0; kt < 2; ++kt) {
                    const bf16x8 vf = *(const bf16x8*)&VTc[sw128(d0 + c, (half * 2 + kt) * 32 + 8 * g)];
                    oacc[dt] = MFMA(pA[kt], vf, oacc[dt]);
                }
            }
        }

        // ---- stage O rows (reuse QBc), out-proj accumulate ----
#pragma unroll
        for (int dt = 0; dt < 4; ++dt)
#pragma unroll
            for (int r = 0; r < 4; ++r)
                QBc[sw64(mt + 4 * g + r, dt * 16 + c)] = f2bf(oacc[dt][r]);
        bf16x8 oA[2];
#pragma unroll
        for (int kt = 0; kt < 2; ++kt)
            oA[kt] = *(const bf16x8*)&QBc[sw64(mt + c, kt * 32 + 8 * g)];
#pragma unroll
        for (int nt4 = 0; nt4 < 4; ++nt4) {
            const int n0 = nt4 * 16;
#pragma unroll
            for (int kt = 0; kt < 2; ++kt) {
                const bf16x8 wp = *(const bf16x8*)&WpT[(n0 + c) * 512 + h * 64 + kt * 32 + 8 * g];
                projacc[nt4] = MFMA(oA[kt], wp, projacc[nt4]);
            }
        }

        // ---- consume prefetched fragments: project head h+1 into the other buffer ----
        if (h < NH - 1) PROJC(h + 1, bufn);

        __syncthreads();   // one barrier per head
    }

    // ---- epilogue: + bp, coalesced f32 stores ----
    {
        float* og = out + (size_t)b * NM * ND;
#pragma unroll
        for (int nt4 = 0; nt4 < 4; ++nt4) {
            const int n0 = nt4 * 16;
            const float bpv = bp[n0 + c];
#pragma unroll
            for (int r = 0; r < 4; ++r)
                og[(mt + 4 * g + r) * ND + n0 + c] = projacc[nt4][r] + bpv;
        }
    }
}

extern "C" void kernel_launch(void* const* d_in, const int* in_sizes, int n_in,
                              void* d_out, int out_size, void* d_ws, size_t ws_size,
                              hipStream_t stream) {
    const float* x     = (const float*)d_in[0];
    const int*   edges = (const int*)d_in[1];
    const float* Wq    = (const float*)d_in[2];
    const float* bq    = (const float*)d_in[3];
    const float* Wk    = (const float*)d_in[4];
    const float* bk    = (const float*)d_in[5];
    const float* Wv    = (const float*)d_in[6];
    const float* bv    = (const float*)d_in[7];
    const float* eb    = (const float*)d_in[8];
    const float* Wp    = (const float*)d_in[9];
    const float* bp    = (const float*)d_in[10];
    float* out = (float*)d_out;
    ushort_t* ws = (ushort_t*)d_ws;   // needs 262144 B

    hipLaunchKernelGGL(geat_prep, dim3(512), dim3(256), 0, stream, Wq, Wk, Wv, Wp, ws);
    hipLaunchKernelGGL(geat_pipe, dim3(NB), dim3(512), 0, stream,
                       x, edges, bq, bk, bv, eb, bp, ws, out);
}